// Round 8
// baseline (617.484 us; speedup 1.0000x reference)
//
#include <hip/hip_runtime.h>
#include <math.h>

// Fused dual-LeNet + len-19 full convolution + log.
// 2 samples (4 LeNet instances) per block, 256 threads.
// Round-8: peeled-row conv structure (each row read once, both pool windows
// consumed in-iteration, ZERO rolling copies — R7 spent ~13% VALU + serial
// chain on rC=rN copies) + weights streamed from global (VMEM pipe idle,
// L1-hot) as 5-element rows. Live state ~40 floats -> no spill (VGPR<=64).

#define SPB 2            // samples per block
#define P1_IC  148       // s_p1 channel stride (mod 32 = 20)
#define P1_IN  888       // s_p1 instance stride = 6*148 (mod 32 = 24)

__global__ __launch_bounds__(256) void lenet_fused(
    const float* __restrict__ x,     // [B,2,28,28]
    const float* __restrict__ cw1,   // [6,1,5,5]
    const float* __restrict__ cb1,   // [6]
    const float* __restrict__ cw2,   // [16,6,5,5]
    const float* __restrict__ cb2,   // [16]
    const float* __restrict__ fw1,   // [120,256]
    const float* __restrict__ fb1,   // [120]
    const float* __restrict__ fw2,   // [84,120]
    const float* __restrict__ fb2,   // [84]
    const float* __restrict__ fw3,   // [10,84]
    const float* __restrict__ fb3,   // [10]
    float* __restrict__ out)         // [B,19]
{
    const int tid = threadIdx.x;
    const int b0  = blockIdx.x * SPB;

    __shared__ __align__(16) float s_pool[4 * 784];      // 12544 B
    __shared__ __align__(16) float s_p1  [4 * P1_IN];    // 14208 B
    // total 26752 B -> 6 blocks/CU

    float* s_img = s_pool;           // 3136 floats (4 inst x 784)
    float* s_p2  = s_pool;           // 1024
    float* s_f1  = s_pool + 1024;    // 480
    float* s_f2  = s_pool + 1504;    // 336
    float* s_log = s_pool + 1840;    // 40

    // ---- stage images: 784 float4, coalesced ----
    {
        const float4* xb = (const float4*)(x + (size_t)b0 * 1568);
        float4* si = (float4*)s_img;
        for (int i = tid; i < 784; i += 256) si[i] = xb[i];
    }
    __syncthreads();

    // ---- conv1 5x5 (1->6) + pool2x2 + relu ----
    // fixed o = tid%6 (252 lanes); 144 tasks per o = 4inst x 12py x 3g
    if (tid < 252) {
        const int o  = tid % 6;
        const int li = tid / 6;                 // 0..41
        const float* wo  = cw1 + o * 25;
        const float  bia = cb1[o];
#pragma unroll 1
        for (int jj = 0; jj < 4; ++jj) {
            int j = jj * 42 + li;
            if (j >= 144) break;
            int inst = j / 36, rem = j % 36;
            int py = rem / 3, g = rem % 3;
            const float* base = &s_img[inst * 784 + (py * 2) * 28 + g * 8];

            float acc0[8], acc1[8];
#pragma unroll
            for (int i = 0; i < 8; ++i) { acc0[i] = 0.f; acc1[i] = 0.f; }

            // r = 0 : window row 0 of acc0 only
            {
                const float4* rp = (const float4*)base;
                float4 q0 = rp[0], q1 = rp[1], q2 = rp[2];
                float row[12] = {q0.x,q0.y,q0.z,q0.w,q1.x,q1.y,q1.z,q1.w,q2.x,q2.y,q2.z,q2.w};
#pragma unroll
                for (int kx = 0; kx < 5; ++kx) {
                    float wv = wo[kx];
#pragma unroll
                    for (int cc = 0; cc < 8; ++cc)
                        acc0[cc] = fmaf(row[cc + kx], wv, acc0[cc]);
                }
            }
            // r = 1..4 : row read once, both windows consumed (no copies)
#pragma unroll 1
            for (int r = 1; r <= 4; ++r) {
                const float4* rp = (const float4*)(base + r * 28);
                float4 q0 = rp[0], q1 = rp[1], q2 = rp[2];
                float row[12] = {q0.x,q0.y,q0.z,q0.w,q1.x,q1.y,q1.z,q1.w,q2.x,q2.y,q2.z,q2.w};
                const float* whi = wo + r * 5;
                const float* wlo = whi - 5;
#pragma unroll
                for (int kx = 0; kx < 5; ++kx) {
                    float wh = whi[kx];
                    float wl = wlo[kx];
#pragma unroll
                    for (int cc = 0; cc < 8; ++cc) {
                        acc0[cc] = fmaf(row[cc + kx], wh, acc0[cc]);
                        acc1[cc] = fmaf(row[cc + kx], wl, acc1[cc]);
                    }
                }
            }
            // r = 5 : window row 4 of acc1 only
            {
                const float4* rp = (const float4*)(base + 5 * 28);
                float4 q0 = rp[0], q1 = rp[1], q2 = rp[2];
                float row[12] = {q0.x,q0.y,q0.z,q0.w,q1.x,q1.y,q1.z,q1.w,q2.x,q2.y,q2.z,q2.w};
                const float* wlo = wo + 20;
#pragma unroll
                for (int kx = 0; kx < 5; ++kx) {
                    float wl = wlo[kx];
#pragma unroll
                    for (int cc = 0; cc < 8; ++cc)
                        acc1[cc] = fmaf(row[cc + kx], wl, acc1[cc]);
                }
            }
            float4 res;
            res.x = fmaxf(fmaxf(fmaxf(acc0[0], acc0[1]), fmaxf(acc1[0], acc1[1])) + bia, 0.f);
            res.y = fmaxf(fmaxf(fmaxf(acc0[2], acc0[3]), fmaxf(acc1[2], acc1[3])) + bia, 0.f);
            res.z = fmaxf(fmaxf(fmaxf(acc0[4], acc0[5]), fmaxf(acc1[4], acc1[5])) + bia, 0.f);
            res.w = fmaxf(fmaxf(fmaxf(acc0[6], acc0[7]), fmaxf(acc1[6], acc1[7])) + bia, 0.f);
            *(float4*)&s_p1[inst * P1_IN + o * P1_IC + py * 12 + g * 4] = res;
        }
    }
    __syncthreads();

    // ---- conv2 5x5 (6->16) + pool2x2 + relu : exactly 256 tasks, 1 round ----
    {
        const int o    = tid & 15;
        const int u    = tid >> 4;
        const int inst = u & 3;
        const int py   = u >> 2;
        const float* wbase = cw2 + o * 150;
        const float  bia   = cb2[o];
        const float* pb    = &s_p1[inst * P1_IN + (py * 2) * 12];

        float accA[8], accB[8];
#pragma unroll
        for (int i = 0; i < 8; ++i) { accA[i] = 0.f; accB[i] = 0.f; }

#pragma unroll 1
        for (int ic = 0; ic < 6; ++ic) {
            const float* prow = pb + ic * P1_IC;
            const float* wic  = wbase + ic * 25;

            // r = 0
            {
                const float4* rp = (const float4*)prow;
                float4 q0 = rp[0], q1 = rp[1], q2 = rp[2];
                float row[12] = {q0.x,q0.y,q0.z,q0.w,q1.x,q1.y,q1.z,q1.w,q2.x,q2.y,q2.z,q2.w};
#pragma unroll
                for (int kx = 0; kx < 5; ++kx) {
                    float wv = wic[kx];
#pragma unroll
                    for (int cc = 0; cc < 8; ++cc)
                        accA[cc] = fmaf(row[cc + kx], wv, accA[cc]);
                }
            }
            // r = 1..4
#pragma unroll 1
            for (int r = 1; r <= 4; ++r) {
                const float4* rp = (const float4*)(prow + r * 12);
                float4 q0 = rp[0], q1 = rp[1], q2 = rp[2];
                float row[12] = {q0.x,q0.y,q0.z,q0.w,q1.x,q1.y,q1.z,q1.w,q2.x,q2.y,q2.z,q2.w};
                const float* whi = wic + r * 5;
                const float* wlo = whi - 5;
#pragma unroll
                for (int kx = 0; kx < 5; ++kx) {
                    float wh = whi[kx];
                    float wl = wlo[kx];
#pragma unroll
                    for (int cc = 0; cc < 8; ++cc) {
                        accA[cc] = fmaf(row[cc + kx], wh, accA[cc]);
                        accB[cc] = fmaf(row[cc + kx], wl, accB[cc]);
                    }
                }
            }
            // r = 5
            {
                const float4* rp = (const float4*)(prow + 5 * 12);
                float4 q0 = rp[0], q1 = rp[1], q2 = rp[2];
                float row[12] = {q0.x,q0.y,q0.z,q0.w,q1.x,q1.y,q1.z,q1.w,q2.x,q2.y,q2.z,q2.w};
                const float* wlo = wic + 20;
#pragma unroll
                for (int kx = 0; kx < 5; ++kx) {
                    float wl = wlo[kx];
#pragma unroll
                    for (int cc = 0; cc < 8; ++cc)
                        accB[cc] = fmaf(row[cc + kx], wl, accB[cc]);
                }
            }
        }
        float4 res;
        res.x = fmaxf(fmaxf(fmaxf(accA[0], accA[1]), fmaxf(accB[0], accB[1])) + bia, 0.f);
        res.y = fmaxf(fmaxf(fmaxf(accA[2], accA[3]), fmaxf(accB[2], accB[3])) + bia, 0.f);
        res.z = fmaxf(fmaxf(fmaxf(accA[4], accA[5]), fmaxf(accB[4], accB[5])) + bia, 0.f);
        res.w = fmaxf(fmaxf(fmaxf(accA[6], accA[7]), fmaxf(accB[6], accB[7])) + bia, 0.f);
        *(float4*)&s_p2[inst * 256 + o * 16 + py * 4] = res;
    }
    __syncthreads();

    // ---- fc1: 256 -> 120, relu. 240 lanes, 2 instances each ----
    if (tid < 240) {
        int o  = tid % 120;
        int pr = tid / 120;
        const float4* wr = (const float4*)(fw1 + o * 256);
        const float4* q0 = (const float4*)(s_p2 + (2 * pr    ) * 256);
        const float4* q1 = (const float4*)(s_p2 + (2 * pr + 1) * 256);
        float a0 = 0.f, a1 = 0.f;
#pragma unroll 4
        for (int k = 0; k < 64; ++k) {
            float4 w4 = wr[k];
            float4 p;
            p = q0[k]; a0 = fmaf(w4.x,p.x,a0); a0 = fmaf(w4.y,p.y,a0); a0 = fmaf(w4.z,p.z,a0); a0 = fmaf(w4.w,p.w,a0);
            p = q1[k]; a1 = fmaf(w4.x,p.x,a1); a1 = fmaf(w4.y,p.y,a1); a1 = fmaf(w4.z,p.z,a1); a1 = fmaf(w4.w,p.w,a1);
        }
        float bb = fb1[o];
        s_f1[(2 * pr    ) * 120 + o] = fmaxf(a0 + bb, 0.f);
        s_f1[(2 * pr + 1) * 120 + o] = fmaxf(a1 + bb, 0.f);
    }
    __syncthreads();

    // ---- fc2: 120 -> 84, relu. 168 lanes, 2 instances each ----
    if (tid < 168) {
        int o  = tid % 84;
        int pr = tid / 84;
        const float4* wr = (const float4*)(fw2 + o * 120);
        const float4* q0 = (const float4*)(s_f1 + (2 * pr    ) * 120);
        const float4* q1 = (const float4*)(s_f1 + (2 * pr + 1) * 120);
        float a0 = 0.f, a1 = 0.f;
#pragma unroll 5
        for (int k = 0; k < 30; ++k) {
            float4 w4 = wr[k];
            float4 p;
            p = q0[k]; a0 = fmaf(w4.x,p.x,a0); a0 = fmaf(w4.y,p.y,a0); a0 = fmaf(w4.z,p.z,a0); a0 = fmaf(w4.w,p.w,a0);
            p = q1[k]; a1 = fmaf(w4.x,p.x,a1); a1 = fmaf(w4.y,p.y,a1); a1 = fmaf(w4.z,p.z,a1); a1 = fmaf(w4.w,p.w,a1);
        }
        float bb = fb2[o];
        s_f2[(2 * pr    ) * 84 + o] = fmaxf(a0 + bb, 0.f);
        s_f2[(2 * pr + 1) * 84 + o] = fmaxf(a1 + bb, 0.f);
    }
    __syncthreads();

    // ---- fc3: 84 -> 10. 40 lanes ----
    if (tid < 40) {
        int o    = tid % 10;
        int inst = tid / 10;
        const float4* wr = (const float4*)(fw3 + o * 84);
        const float4* q0 = (const float4*)(s_f2 + inst * 84);
        float a0 = 0.f;
#pragma unroll
        for (int k = 0; k < 21; ++k) {
            float4 w4 = wr[k];
            float4 p = q0[k];
            a0 = fmaf(w4.x,p.x,a0); a0 = fmaf(w4.y,p.y,a0); a0 = fmaf(w4.z,p.z,a0); a0 = fmaf(w4.w,p.w,a0);
        }
        s_log[inst * 10 + o] = a0 + fb3[o];
    }
    __syncthreads();

    // ---- softmax (in-lane) + full convolution (len 19) + log ----
    if (tid < 19 * SPB) {
        int ls = tid / 19;
        int t  = tid % 19;
        const float* la = &s_log[(ls * 2 + 0) * 10];
        const float* lb = &s_log[(ls * 2 + 1) * 10];
        float pa[10], pb[10];
        float mxa = la[0], mxb = lb[0];
#pragma unroll
        for (int j = 1; j < 10; ++j) { mxa = fmaxf(mxa, la[j]); mxb = fmaxf(mxb, lb[j]); }
        float sa = 0.f, sb = 0.f;
#pragma unroll
        for (int j = 0; j < 10; ++j) {
            pa[j] = __expf(la[j] - mxa); sa += pa[j];
            pb[j] = __expf(lb[j] - mxb); sb += pb[j];
        }
        float inv = 1.f / (sa * sb);
        int jlo = t - 9 > 0 ? t - 9 : 0;
        int jhi = t < 9 ? t : 9;
        float z = 0.f;
        for (int j = jlo; j <= jhi; ++j)
            z += pa[j] * pb[t - j];
        out[(size_t)(b0 + ls) * 19 + t] = __logf(z * inv);
    }
}

extern "C" void kernel_launch(void* const* d_in, const int* in_sizes, int n_in,
                              void* d_out, int out_size, void* d_ws, size_t ws_size,
                              hipStream_t stream) {
    const float* x   = (const float*)d_in[0];
    const float* cw1 = (const float*)d_in[1];
    const float* cb1 = (const float*)d_in[2];
    const float* cw2 = (const float*)d_in[3];
    const float* cb2 = (const float*)d_in[4];
    const float* fw1 = (const float*)d_in[5];
    const float* fb1 = (const float*)d_in[6];
    const float* fw2 = (const float*)d_in[7];
    const float* fb2 = (const float*)d_in[8];
    const float* fw3 = (const float*)d_in[9];
    const float* fb3 = (const float*)d_in[10];
    float* out = (float*)d_out;

    const int B = in_sizes[0] / (2 * 28 * 28);   // 16384

    lenet_fused<<<B / SPB, 256, 0, stream>>>(x, cw1, cb1, cw2, cb2,
                                             fw1, fb1, fw2, fb2, fw3, fb3, out);
}

// Round 9
// 477.818 us; speedup vs baseline: 1.2923x; 1.2923x over previous
//
#include <hip/hip_runtime.h>
#include <math.h>

// Fused dual-LeNet + len-19 full convolution + log.
// 2 samples (4 LeNet instances) per block, 256 threads.
// Round-9 = merge of proven pieces:
//  * R5 base: single-pass staging, conv weights in LDS (transposed, broadcast
//    reads), o-fastest task maps, 64-VGPR-fit peeled conv bodies.  (R5 = best
//    counter time 420 us, 66.8% VALU; global-weight variants R7/R8 regressed
//    on vmcnt serialization.)
//  * R7 padding: s_p1 strides 148/888 (mod32 = 20/24) -> conv2 activation
//    reads provably conflict-free (4.18e7 -> 8.9e6 measured).
//  * R8 conv2 shape: 256 tasks = 1 full round, full 4-wide pooled row/lane.
//  * ping-pong weight rows (wa/wb, no copies): halves conv weight LDS reads.
//  * merged softmax into output lanes (saves a barrier + serial phase).

#define SPB 2            // samples per block
#define P1_IC  148       // s_p1 channel stride (mod 32 = 20)
#define P1_IN  888       // s_p1 instance stride = 6*148 (mod 32 = 24)

__global__ __launch_bounds__(256) void lenet_fused(
    const float* __restrict__ x,     // [B,2,28,28]
    const float* __restrict__ cw1,   // [6,1,5,5]
    const float* __restrict__ cb1,   // [6]
    const float* __restrict__ cw2,   // [16,6,5,5]
    const float* __restrict__ cb2,   // [16]
    const float* __restrict__ fw1,   // [120,256]
    const float* __restrict__ fb1,   // [120]
    const float* __restrict__ fw2,   // [84,120]
    const float* __restrict__ fb2,   // [84]
    const float* __restrict__ fw3,   // [10,84]
    const float* __restrict__ fb3,   // [10]
    float* __restrict__ out)         // [B,19]
{
    const int tid = threadIdx.x;
    const int b0  = blockIdx.x * SPB;

    __shared__ __align__(16) float s_pool[4 * 784];      // 12544 B (imgs; reused)
    __shared__ __align__(16) float s_p1  [4 * P1_IN];    // 14208 B
    __shared__ __align__(16) float s_w1t [25 * 8];       //   800 B  [k][o]
    __shared__ float s_b1[8];
    __shared__ __align__(16) float s_w2t [150 * 16];     //  9600 B  [ic*25+k][o]
    __shared__ float s_b2[16];
    // total ~37.2 KB -> 4 blocks/CU

    float* s_img = s_pool;           // 3136 floats (4 inst x 784)
    float* s_p2  = s_pool;           // 1024
    float* s_f1  = s_pool + 1024;    // 480
    float* s_f2  = s_pool + 1504;    // 336
    float* s_log = s_pool + 1840;    // 40

    // ---- stage images + weights ----
    {
        const float4* xb = (const float4*)(x + (size_t)b0 * 1568);
        float4* si = (float4*)s_img;
        for (int i = tid; i < 784; i += 256) si[i] = xb[i];
    }
    for (int i = tid; i < 150; i += 256) {       // cw1 -> [k][o], stride 8
        int o = i / 25, k = i % 25;
        s_w1t[k * 8 + o] = cw1[i];
    }
    for (int i = tid; i < 2400; i += 256) {      // cw2 -> [ic*25+k][o], stride 16
        int o = i / 150, r = i % 150;
        s_w2t[r * 16 + o] = cw2[i];
    }
    if (tid < 6)  s_b1[tid] = cb1[tid];
    if (tid < 16) s_b2[tid] = cb2[tid];
    __syncthreads();

#define LOAD_ROW12(dst, ptr)                                                   \
    {   const float4* _rp = (const float4*)(ptr);                              \
        float4 _q0 = _rp[0], _q1 = _rp[1], _q2 = _rp[2];                       \
        dst[0]=_q0.x; dst[1]=_q0.y; dst[2]=_q0.z; dst[3]=_q0.w;                \
        dst[4]=_q1.x; dst[5]=_q1.y; dst[6]=_q1.z; dst[7]=_q1.w;                \
        dst[8]=_q2.x; dst[9]=_q2.y; dst[10]=_q2.z; dst[11]=_q2.w; }

#define FMA8(accv, rowv, wv)                                                   \
    _Pragma("unroll")                                                          \
    for (int kx = 0; kx < 5; ++kx) {                                           \
        float _w = (wv)[kx];                                                   \
        _Pragma("unroll")                                                      \
        for (int cc = 0; cc < 8; ++cc)                                         \
            accv[cc] = fmaf((rowv)[cc + kx], _w, accv[cc]);                    \
    }

    // ---- conv1 5x5 (1->6) + pool2x2 + relu : 864 tasks, o fastest ----
#pragma unroll 1
    for (int t = tid; t < 864; t += 256) {
        int o  = t % 6;  int u = t / 6;
        int g  = u % 3;  int v = u / 3;
        int py = v % 12; int inst = v / 12;

        const float* wt   = &s_w1t[o];           // w[k] at wt[k*8]
        const float* base = &s_img[inst * 784 + (py * 2) * 28 + g * 8];

        float acc0[8], acc1[8];
#pragma unroll
        for (int i = 0; i < 8; ++i) { acc0[i] = 0.f; acc1[i] = 0.f; }

        float row[12], wa[5], wb[5];
        // r0: load w-row0 -> wa
        LOAD_ROW12(row, base);
#pragma unroll
        for (int kx = 0; kx < 5; ++kx) wa[kx] = wt[kx * 8];
        FMA8(acc0, row, wa);
        // r1: load w-row1 -> wb ; wlo = wa
        LOAD_ROW12(row, base + 28);
#pragma unroll
        for (int kx = 0; kx < 5; ++kx) wb[kx] = wt[(5 + kx) * 8];
        FMA8(acc0, row, wb); FMA8(acc1, row, wa);
        // r2: wa = w-row2
        LOAD_ROW12(row, base + 56);
#pragma unroll
        for (int kx = 0; kx < 5; ++kx) wa[kx] = wt[(10 + kx) * 8];
        FMA8(acc0, row, wa); FMA8(acc1, row, wb);
        // r3: wb = w-row3
        LOAD_ROW12(row, base + 84);
#pragma unroll
        for (int kx = 0; kx < 5; ++kx) wb[kx] = wt[(15 + kx) * 8];
        FMA8(acc0, row, wb); FMA8(acc1, row, wa);
        // r4: wa = w-row4
        LOAD_ROW12(row, base + 112);
#pragma unroll
        for (int kx = 0; kx < 5; ++kx) wa[kx] = wt[(20 + kx) * 8];
        FMA8(acc0, row, wa); FMA8(acc1, row, wb);
        // r5: acc1 only, w-row4 (= wa)
        LOAD_ROW12(row, base + 140);
        FMA8(acc1, row, wa);

        float bia = s_b1[o];
        float4 res;
        res.x = fmaxf(fmaxf(fmaxf(acc0[0], acc0[1]), fmaxf(acc1[0], acc1[1])) + bia, 0.f);
        res.y = fmaxf(fmaxf(fmaxf(acc0[2], acc0[3]), fmaxf(acc1[2], acc1[3])) + bia, 0.f);
        res.z = fmaxf(fmaxf(fmaxf(acc0[4], acc0[5]), fmaxf(acc1[4], acc1[5])) + bia, 0.f);
        res.w = fmaxf(fmaxf(fmaxf(acc0[6], acc0[7]), fmaxf(acc1[6], acc1[7])) + bia, 0.f);
        *(float4*)&s_p1[inst * P1_IN + o * P1_IC + py * 12 + g * 4] = res;
    }
    __syncthreads();

    // ---- conv2 5x5 (6->16) + pool2x2 + relu : 256 tasks, 1 round ----
    // lanes 0-15 broadcast activation reads; 4 inst-groups land on banks
    // {0,24,16,8} under padded strides -> conflict-free.
    {
        const int o    = tid & 15;
        const int u    = tid >> 4;
        const int inst = u & 3;
        const int py   = u >> 2;
        const float* wt = &s_w2t[o];             // w[ic*25+k] at wt[(ic*25+k)*16]
        const float* pb = &s_p1[inst * P1_IN + (py * 2) * 12];

        float accA[8], accB[8];
#pragma unroll
        for (int i = 0; i < 8; ++i) { accA[i] = 0.f; accB[i] = 0.f; }

#pragma unroll 1
        for (int ic = 0; ic < 6; ++ic) {
            const float* prow = pb + ic * P1_IC;
            const float* wic  = wt + ic * 400;   // (ic*25)*16

            float row[12], wa[5], wb[5];
            LOAD_ROW12(row, prow);
#pragma unroll
            for (int kx = 0; kx < 5; ++kx) wa[kx] = wic[kx * 16];
            FMA8(accA, row, wa);

            LOAD_ROW12(row, prow + 12);
#pragma unroll
            for (int kx = 0; kx < 5; ++kx) wb[kx] = wic[(5 + kx) * 16];
            FMA8(accA, row, wb); FMA8(accB, row, wa);

            LOAD_ROW12(row, prow + 24);
#pragma unroll
            for (int kx = 0; kx < 5; ++kx) wa[kx] = wic[(10 + kx) * 16];
            FMA8(accA, row, wa); FMA8(accB, row, wb);

            LOAD_ROW12(row, prow + 36);
#pragma unroll
            for (int kx = 0; kx < 5; ++kx) wb[kx] = wic[(15 + kx) * 16];
            FMA8(accA, row, wb); FMA8(accB, row, wa);

            LOAD_ROW12(row, prow + 48);
#pragma unroll
            for (int kx = 0; kx < 5; ++kx) wa[kx] = wic[(20 + kx) * 16];
            FMA8(accA, row, wa); FMA8(accB, row, wb);

            LOAD_ROW12(row, prow + 60);
            FMA8(accB, row, wa);
        }
        float bia = cb2[o];
        float4 res;
        res.x = fmaxf(fmaxf(fmaxf(accA[0], accA[1]), fmaxf(accB[0], accB[1])) + bia, 0.f);
        res.y = fmaxf(fmaxf(fmaxf(accA[2], accA[3]), fmaxf(accB[2], accB[3])) + bia, 0.f);
        res.z = fmaxf(fmaxf(fmaxf(accA[4], accA[5]), fmaxf(accB[4], accB[5])) + bia, 0.f);
        res.w = fmaxf(fmaxf(fmaxf(accA[6], accA[7]), fmaxf(accB[6], accB[7])) + bia, 0.f);
        *(float4*)&s_p2[inst * 256 + o * 16 + py * 4] = res;
    }
    __syncthreads();

    // ---- fc1: 256 -> 120, relu. 240 lanes, 2 instances each ----
    if (tid < 240) {
        int o  = tid % 120;
        int pr = tid / 120;
        const float4* wr = (const float4*)(fw1 + o * 256);
        const float4* q0 = (const float4*)(s_p2 + (2 * pr    ) * 256);
        const float4* q1 = (const float4*)(s_p2 + (2 * pr + 1) * 256);
        float a0 = 0.f, a1 = 0.f;
#pragma unroll 4
        for (int k = 0; k < 64; ++k) {
            float4 w4 = wr[k];
            float4 p;
            p = q0[k]; a0 = fmaf(w4.x,p.x,a0); a0 = fmaf(w4.y,p.y,a0); a0 = fmaf(w4.z,p.z,a0); a0 = fmaf(w4.w,p.w,a0);
            p = q1[k]; a1 = fmaf(w4.x,p.x,a1); a1 = fmaf(w4.y,p.y,a1); a1 = fmaf(w4.z,p.z,a1); a1 = fmaf(w4.w,p.w,a1);
        }
        float bb = fb1[o];
        s_f1[(2 * pr    ) * 120 + o] = fmaxf(a0 + bb, 0.f);
        s_f1[(2 * pr + 1) * 120 + o] = fmaxf(a1 + bb, 0.f);
    }
    __syncthreads();

    // ---- fc2: 120 -> 84, relu. 168 lanes, 2 instances each ----
    if (tid < 168) {
        int o  = tid % 84;
        int pr = tid / 84;
        const float4* wr = (const float4*)(fw2 + o * 120);
        const float4* q0 = (const float4*)(s_f1 + (2 * pr    ) * 120);
        const float4* q1 = (const float4*)(s_f1 + (2 * pr + 1) * 120);
        float a0 = 0.f, a1 = 0.f;
#pragma unroll 5
        for (int k = 0; k < 30; ++k) {
            float4 w4 = wr[k];
            float4 p;
            p = q0[k]; a0 = fmaf(w4.x,p.x,a0); a0 = fmaf(w4.y,p.y,a0); a0 = fmaf(w4.z,p.z,a0); a0 = fmaf(w4.w,p.w,a0);
            p = q1[k]; a1 = fmaf(w4.x,p.x,a1); a1 = fmaf(w4.y,p.y,a1); a1 = fmaf(w4.z,p.z,a1); a1 = fmaf(w4.w,p.w,a1);
        }
        float bb = fb2[o];
        s_f2[(2 * pr    ) * 84 + o] = fmaxf(a0 + bb, 0.f);
        s_f2[(2 * pr + 1) * 84 + o] = fmaxf(a1 + bb, 0.f);
    }
    __syncthreads();

    // ---- fc3: 84 -> 10. 40 lanes ----
    if (tid < 40) {
        int o    = tid % 10;
        int inst = tid / 10;
        const float4* wr = (const float4*)(fw3 + o * 84);
        const float4* q0 = (const float4*)(s_f2 + inst * 84);
        float a0 = 0.f;
#pragma unroll
        for (int k = 0; k < 21; ++k) {
            float4 w4 = wr[k];
            float4 p = q0[k];
            a0 = fmaf(w4.x,p.x,a0); a0 = fmaf(w4.y,p.y,a0); a0 = fmaf(w4.z,p.z,a0); a0 = fmaf(w4.w,p.w,a0);
        }
        s_log[inst * 10 + o] = a0 + fb3[o];
    }
    __syncthreads();

    // ---- softmax (in-lane) + full convolution (len 19) + log ----
    if (tid < 19 * SPB) {
        int ls = tid / 19;
        int t  = tid % 19;
        const float* la = &s_log[(ls * 2 + 0) * 10];
        const float* lb = &s_log[(ls * 2 + 1) * 10];
        float pa[10], pb[10];
        float mxa = la[0], mxb = lb[0];
#pragma unroll
        for (int j = 1; j < 10; ++j) { mxa = fmaxf(mxa, la[j]); mxb = fmaxf(mxb, lb[j]); }
        float sa = 0.f, sb = 0.f;
#pragma unroll
        for (int j = 0; j < 10; ++j) {
            pa[j] = __expf(la[j] - mxa); sa += pa[j];
            pb[j] = __expf(lb[j] - mxb); sb += pb[j];
        }
        float inv = 1.f / (sa * sb);
        int jlo = t - 9 > 0 ? t - 9 : 0;
        int jhi = t < 9 ? t : 9;
        float z = 0.f;
        for (int j = jlo; j <= jhi; ++j)
            z += pa[j] * pb[t - j];
        out[(size_t)(b0 + ls) * 19 + t] = __logf(z * inv);
    }
}

extern "C" void kernel_launch(void* const* d_in, const int* in_sizes, int n_in,
                              void* d_out, int out_size, void* d_ws, size_t ws_size,
                              hipStream_t stream) {
    const float* x   = (const float*)d_in[0];
    const float* cw1 = (const float*)d_in[1];
    const float* cb1 = (const float*)d_in[2];
    const float* cw2 = (const float*)d_in[3];
    const float* cb2 = (const float*)d_in[4];
    const float* fw1 = (const float*)d_in[5];
    const float* fb1 = (const float*)d_in[6];
    const float* fw2 = (const float*)d_in[7];
    const float* fb2 = (const float*)d_in[8];
    const float* fw3 = (const float*)d_in[9];
    const float* fb3 = (const float*)d_in[10];
    float* out = (float*)d_out;

    const int B = in_sizes[0] / (2 * 28 * 28);   // 16384

    lenet_fused<<<B / SPB, 256, 0, stream>>>(x, cw1, cb1, cw2, cb2,
                                             fw1, fb1, fw2, fb2, fw3, fb3, out);
}

// Round 10
// 439.693 us; speedup vs baseline: 1.4044x; 1.0867x over previous
//
#include <hip/hip_runtime.h>
#include <math.h>

// Fused dual-LeNet + len-19 full convolution + log.
// 2 samples (4 LeNet instances) per block, 256 threads.
// Round-10: conv2 switches to v_dot2_f32_f16 (__builtin_amdgcn_fdot2):
//  * conv1 outputs stored as f16 channel-PAIRS (half2 = channels 2i,2i+1 at
//    one spatial position); conv2 weights staged as matching half2 pairs.
//  * one dot2 = 2 MACs with fp32 accumulate -> conv2 instruction count
//    halves (conv2 was 54% of block VALU ops in R9).
//  * s_p1 14.2->7.0 KB, s_w2 9.6->4.8 KB: LDS 25.3 KB -> 6 blocks/CU
//    (R9: 4), occupancy cap 50%->75%.
// Everything else = R9 (best so far: 404 us counter): LDS-resident weights
// with broadcast reads, ping-pong weight rows, padded strides, merged tail.

#define SPB 2            // samples per block
#define P1H_IN 440       // s_p1h instance stride in half2 (mod 32 = 24)
#define P1H_IC 144       // channel-pair stride in half2 (3 pairs per inst)

typedef _Float16 f16x2 __attribute__((ext_vector_type(2)));

__global__ __launch_bounds__(256) void lenet_fused(
    const float* __restrict__ x,     // [B,2,28,28]
    const float* __restrict__ cw1,   // [6,1,5,5]
    const float* __restrict__ cb1,   // [6]
    const float* __restrict__ cw2,   // [16,6,5,5]
    const float* __restrict__ cb2,   // [16]
    const float* __restrict__ fw1,   // [120,256]
    const float* __restrict__ fb1,   // [120]
    const float* __restrict__ fw2,   // [84,120]
    const float* __restrict__ fb2,   // [84]
    const float* __restrict__ fw3,   // [10,84]
    const float* __restrict__ fb3,   // [10]
    float* __restrict__ out)         // [B,19]
{
    const int tid = threadIdx.x;
    const int b0  = blockIdx.x * SPB;

    __shared__ __align__(16) float s_pool[4 * 784];      // 12544 B (imgs; reused)
    __shared__ __align__(16) f16x2 s_p1h [4 * P1H_IN];   //  7040 B
    __shared__ __align__(16) float s_w1t [25 * 8];       //   800 B  [k][o]
    __shared__ float s_b1[8];
    __shared__ __align__(16) f16x2 s_w2h [1200];         //  4800 B  [icp][k][o]
    __shared__ float s_b2[16];
    // total ~25.4 KB -> 6 blocks/CU

    float* s_img = s_pool;           // 3136 floats (4 inst x 784)
    float* s_p2  = s_pool;           // 1024
    float* s_f1  = s_pool + 1024;    // 480
    float* s_f2  = s_pool + 1504;    // 336
    float* s_log = s_pool + 1840;    // 40

    // ---- stage images + weights ----
    {
        const float4* xb = (const float4*)(x + (size_t)b0 * 1568);
        float4* si = (float4*)s_img;
        for (int i = tid; i < 784; i += 256) si[i] = xb[i];
    }
    for (int i = tid; i < 150; i += 256) {       // cw1 -> [k][o], stride 8
        int o = i / 25, k = i % 25;
        s_w1t[k * 8 + o] = cw1[i];
    }
    for (int i = tid; i < 1200; i += 256) {      // cw2 -> half2 pairs [icp][k][o]
        int icp = i / 400, r = i % 400;
        int k = r / 16, o = r % 16;
        float we = cw2[o * 150 + (2 * icp    ) * 25 + k];
        float wo = cw2[o * 150 + (2 * icp + 1) * 25 + k];
        f16x2 w2; w2.x = (_Float16)we; w2.y = (_Float16)wo;
        s_w2h[i] = w2;
    }
    if (tid < 6)  s_b1[tid] = cb1[tid];
    if (tid < 16) s_b2[tid] = cb2[tid];
    __syncthreads();

#define LOAD_ROW12(dst, ptr)                                                   \
    {   const float4* _rp = (const float4*)(ptr);                              \
        float4 _q0 = _rp[0], _q1 = _rp[1], _q2 = _rp[2];                       \
        dst[0]=_q0.x; dst[1]=_q0.y; dst[2]=_q0.z; dst[3]=_q0.w;                \
        dst[4]=_q1.x; dst[5]=_q1.y; dst[6]=_q1.z; dst[7]=_q1.w;                \
        dst[8]=_q2.x; dst[9]=_q2.y; dst[10]=_q2.z; dst[11]=_q2.w; }

#define FMA8(accv, rowv, wv)                                                   \
    _Pragma("unroll")                                                          \
    for (int kx = 0; kx < 5; ++kx) {                                           \
        float _w = (wv)[kx];                                                   \
        _Pragma("unroll")                                                      \
        for (int cc = 0; cc < 8; ++cc)                                         \
            accv[cc] = fmaf((rowv)[cc + kx], _w, accv[cc]);                    \
    }

    // 12 half2 = 3 float4 (16B-aligned: all strides are multiples of 4 half2)
#define LOADH12(dst, ptr)                                                      \
    {   const float4* _rp = (const float4*)(ptr);                              \
        float4 _q0 = _rp[0], _q1 = _rp[1], _q2 = _rp[2];                       \
        dst[0]=__builtin_bit_cast(f16x2,_q0.x); dst[1]=__builtin_bit_cast(f16x2,_q0.y); \
        dst[2]=__builtin_bit_cast(f16x2,_q0.z); dst[3]=__builtin_bit_cast(f16x2,_q0.w); \
        dst[4]=__builtin_bit_cast(f16x2,_q1.x); dst[5]=__builtin_bit_cast(f16x2,_q1.y); \
        dst[6]=__builtin_bit_cast(f16x2,_q1.z); dst[7]=__builtin_bit_cast(f16x2,_q1.w); \
        dst[8]=__builtin_bit_cast(f16x2,_q2.x); dst[9]=__builtin_bit_cast(f16x2,_q2.y); \
        dst[10]=__builtin_bit_cast(f16x2,_q2.z); dst[11]=__builtin_bit_cast(f16x2,_q2.w); }

#define DOT8(accv, rowv, wv)                                                   \
    _Pragma("unroll")                                                          \
    for (int kx = 0; kx < 5; ++kx) {                                           \
        f16x2 _w = (wv)[kx];                                                   \
        _Pragma("unroll")                                                      \
        for (int cc = 0; cc < 8; ++cc)                                         \
            accv[cc] = __builtin_amdgcn_fdot2((rowv)[cc + kx], _w, accv[cc], false); \
    }

    // ---- conv1 5x5 (1->6) + pool2x2 + relu : 864 tasks, o fastest ----
#pragma unroll 1
    for (int t = tid; t < 864; t += 256) {
        int o  = t % 6;  int u = t / 6;
        int g  = u % 3;  int v = u / 3;
        int py = v % 12; int inst = v / 12;

        const float* wt   = &s_w1t[o];           // w[k] at wt[k*8]
        const float* base = &s_img[inst * 784 + (py * 2) * 28 + g * 8];

        float acc0[8], acc1[8];
#pragma unroll
        for (int i = 0; i < 8; ++i) { acc0[i] = 0.f; acc1[i] = 0.f; }

        float row[12], wa[5], wb[5];
        LOAD_ROW12(row, base);
#pragma unroll
        for (int kx = 0; kx < 5; ++kx) wa[kx] = wt[kx * 8];
        FMA8(acc0, row, wa);
        LOAD_ROW12(row, base + 28);
#pragma unroll
        for (int kx = 0; kx < 5; ++kx) wb[kx] = wt[(5 + kx) * 8];
        FMA8(acc0, row, wb); FMA8(acc1, row, wa);
        LOAD_ROW12(row, base + 56);
#pragma unroll
        for (int kx = 0; kx < 5; ++kx) wa[kx] = wt[(10 + kx) * 8];
        FMA8(acc0, row, wa); FMA8(acc1, row, wb);
        LOAD_ROW12(row, base + 84);
#pragma unroll
        for (int kx = 0; kx < 5; ++kx) wb[kx] = wt[(15 + kx) * 8];
        FMA8(acc0, row, wb); FMA8(acc1, row, wa);
        LOAD_ROW12(row, base + 112);
#pragma unroll
        for (int kx = 0; kx < 5; ++kx) wa[kx] = wt[(20 + kx) * 8];
        FMA8(acc0, row, wa); FMA8(acc1, row, wb);
        LOAD_ROW12(row, base + 140);
        FMA8(acc1, row, wa);

        float bia = s_b1[o];
        float m0 = fmaxf(fmaxf(fmaxf(acc0[0], acc0[1]), fmaxf(acc1[0], acc1[1])) + bia, 0.f);
        float m1 = fmaxf(fmaxf(fmaxf(acc0[2], acc0[3]), fmaxf(acc1[2], acc1[3])) + bia, 0.f);
        float m2 = fmaxf(fmaxf(fmaxf(acc0[4], acc0[5]), fmaxf(acc1[4], acc1[5])) + bia, 0.f);
        float m3 = fmaxf(fmaxf(fmaxf(acc0[6], acc0[7]), fmaxf(acc1[6], acc1[7])) + bia, 0.f);

        // store as f16 into channel-pair layout: half2[inst][o>>1][py][px], lane o&1
        _Float16* dst = (_Float16*)&s_p1h[inst * P1H_IN + (o >> 1) * P1H_IC + py * 12 + g * 4];
        dst += (o & 1);
        dst[0] = (_Float16)m0; dst[2] = (_Float16)m1;
        dst[4] = (_Float16)m2; dst[6] = (_Float16)m3;
    }
    __syncthreads();

    // ---- conv2 5x5 (6->16) + pool2x2 + relu : 256 tasks, 1 round, dot2 ----
    // half2 rows carry 2 input channels; 4 inst-groups at banks {0,24,16,8}.
    {
        const int o    = tid & 15;
        const int u    = tid >> 4;
        const int inst = u & 3;
        const int py   = u >> 2;
        const f16x2* wt = s_w2h + o;             // + icp*400 + k*16
        const f16x2* pb = s_p1h + inst * P1H_IN + (py * 2) * 12;

        float accA[8], accB[8];
#pragma unroll
        for (int i = 0; i < 8; ++i) { accA[i] = 0.f; accB[i] = 0.f; }

#pragma unroll 1
        for (int icp = 0; icp < 3; ++icp) {
            const f16x2* prow = pb + icp * P1H_IC;
            const f16x2* wic  = wt + icp * 400;

            f16x2 row[12], wa[5], wb[5];
            LOADH12(row, prow);
#pragma unroll
            for (int kx = 0; kx < 5; ++kx) wa[kx] = wic[kx * 16];
            DOT8(accA, row, wa);

            LOADH12(row, prow + 12);
#pragma unroll
            for (int kx = 0; kx < 5; ++kx) wb[kx] = wic[(5 + kx) * 16];
            DOT8(accA, row, wb); DOT8(accB, row, wa);

            LOADH12(row, prow + 24);
#pragma unroll
            for (int kx = 0; kx < 5; ++kx) wa[kx] = wic[(10 + kx) * 16];
            DOT8(accA, row, wa); DOT8(accB, row, wb);

            LOADH12(row, prow + 36);
#pragma unroll
            for (int kx = 0; kx < 5; ++kx) wb[kx] = wic[(15 + kx) * 16];
            DOT8(accA, row, wb); DOT8(accB, row, wa);

            LOADH12(row, prow + 48);
#pragma unroll
            for (int kx = 0; kx < 5; ++kx) wa[kx] = wic[(20 + kx) * 16];
            DOT8(accA, row, wa); DOT8(accB, row, wb);

            LOADH12(row, prow + 60);
            DOT8(accB, row, wa);
        }
        float bia = s_b2[o];
        float4 res;
        res.x = fmaxf(fmaxf(fmaxf(accA[0], accA[1]), fmaxf(accB[0], accB[1])) + bia, 0.f);
        res.y = fmaxf(fmaxf(fmaxf(accA[2], accA[3]), fmaxf(accB[2], accB[3])) + bia, 0.f);
        res.z = fmaxf(fmaxf(fmaxf(accA[4], accA[5]), fmaxf(accB[4], accB[5])) + bia, 0.f);
        res.w = fmaxf(fmaxf(fmaxf(accA[6], accA[7]), fmaxf(accB[6], accB[7])) + bia, 0.f);
        *(float4*)&s_p2[inst * 256 + o * 16 + py * 4] = res;
    }
    __syncthreads();

    // ---- fc1: 256 -> 120, relu. 240 lanes, 2 instances each ----
    if (tid < 240) {
        int o  = tid % 120;
        int pr = tid / 120;
        const float4* wr = (const float4*)(fw1 + o * 256);
        const float4* q0 = (const float4*)(s_p2 + (2 * pr    ) * 256);
        const float4* q1 = (const float4*)(s_p2 + (2 * pr + 1) * 256);
        float a0 = 0.f, a1 = 0.f;
#pragma unroll 4
        for (int k = 0; k < 64; ++k) {
            float4 w4 = wr[k];
            float4 p;
            p = q0[k]; a0 = fmaf(w4.x,p.x,a0); a0 = fmaf(w4.y,p.y,a0); a0 = fmaf(w4.z,p.z,a0); a0 = fmaf(w4.w,p.w,a0);
            p = q1[k]; a1 = fmaf(w4.x,p.x,a1); a1 = fmaf(w4.y,p.y,a1); a1 = fmaf(w4.z,p.z,a1); a1 = fmaf(w4.w,p.w,a1);
        }
        float bb = fb1[o];
        s_f1[(2 * pr    ) * 120 + o] = fmaxf(a0 + bb, 0.f);
        s_f1[(2 * pr + 1) * 120 + o] = fmaxf(a1 + bb, 0.f);
    }
    __syncthreads();

    // ---- fc2: 120 -> 84, relu. 168 lanes, 2 instances each ----
    if (tid < 168) {
        int o  = tid % 84;
        int pr = tid / 84;
        const float4* wr = (const float4*)(fw2 + o * 120);
        const float4* q0 = (const float4*)(s_f1 + (2 * pr    ) * 120);
        const float4* q1 = (const float4*)(s_f1 + (2 * pr + 1) * 120);
        float a0 = 0.f, a1 = 0.f;
#pragma unroll 5
        for (int k = 0; k < 30; ++k) {
            float4 w4 = wr[k];
            float4 p;
            p = q0[k]; a0 = fmaf(w4.x,p.x,a0); a0 = fmaf(w4.y,p.y,a0); a0 = fmaf(w4.z,p.z,a0); a0 = fmaf(w4.w,p.w,a0);
            p = q1[k]; a1 = fmaf(w4.x,p.x,a1); a1 = fmaf(w4.y,p.y,a1); a1 = fmaf(w4.z,p.z,a1); a1 = fmaf(w4.w,p.w,a1);
        }
        float bb = fb2[o];
        s_f2[(2 * pr    ) * 84 + o] = fmaxf(a0 + bb, 0.f);
        s_f2[(2 * pr + 1) * 84 + o] = fmaxf(a1 + bb, 0.f);
    }
    __syncthreads();

    // ---- fc3: 84 -> 10. 40 lanes ----
    if (tid < 40) {
        int o    = tid % 10;
        int inst = tid / 10;
        const float4* wr = (const float4*)(fw3 + o * 84);
        const float4* q0 = (const float4*)(s_f2 + inst * 84);
        float a0 = 0.f;
#pragma unroll
        for (int k = 0; k < 21; ++k) {
            float4 w4 = wr[k];
            float4 p = q0[k];
            a0 = fmaf(w4.x,p.x,a0); a0 = fmaf(w4.y,p.y,a0); a0 = fmaf(w4.z,p.z,a0); a0 = fmaf(w4.w,p.w,a0);
        }
        s_log[inst * 10 + o] = a0 + fb3[o];
    }
    __syncthreads();

    // ---- softmax (in-lane) + full convolution (len 19) + log ----
    if (tid < 19 * SPB) {
        int ls = tid / 19;
        int t  = tid % 19;
        const float* la = &s_log[(ls * 2 + 0) * 10];
        const float* lb = &s_log[(ls * 2 + 1) * 10];
        float pa[10], pb[10];
        float mxa = la[0], mxb = lb[0];
#pragma unroll
        for (int j = 1; j < 10; ++j) { mxa = fmaxf(mxa, la[j]); mxb = fmaxf(mxb, lb[j]); }
        float sa = 0.f, sb = 0.f;
#pragma unroll
        for (int j = 0; j < 10; ++j) {
            pa[j] = __expf(la[j] - mxa); sa += pa[j];
            pb[j] = __expf(lb[j] - mxb); sb += pb[j];
        }
        float inv = 1.f / (sa * sb);
        int jlo = t - 9 > 0 ? t - 9 : 0;
        int jhi = t < 9 ? t : 9;
        float z = 0.f;
        for (int j = jlo; j <= jhi; ++j)
            z += pa[j] * pb[t - j];
        out[(size_t)(b0 + ls) * 19 + t] = __logf(z * inv);
    }
}

extern "C" void kernel_launch(void* const* d_in, const int* in_sizes, int n_in,
                              void* d_out, int out_size, void* d_ws, size_t ws_size,
                              hipStream_t stream) {
    const float* x   = (const float*)d_in[0];
    const float* cw1 = (const float*)d_in[1];
    const float* cb1 = (const float*)d_in[2];
    const float* cw2 = (const float*)d_in[3];
    const float* cb2 = (const float*)d_in[4];
    const float* fw1 = (const float*)d_in[5];
    const float* fb1 = (const float*)d_in[6];
    const float* fw2 = (const float*)d_in[7];
    const float* fb2 = (const float*)d_in[8];
    const float* fw3 = (const float*)d_in[9];
    const float* fb3 = (const float*)d_in[10];
    float* out = (float*)d_out;

    const int B = in_sizes[0] / (2 * 28 * 28);   // 16384

    lenet_fused<<<B / SPB, 256, 0, stream>>>(x, cw1, cb1, cw2, cb2,
                                             fw1, fb1, fw2, fb2, fw3, fb3, out);
}